// Round 5
// baseline (26.427 us; speedup 1.0000x reference)
//
#include <hip/hip_runtime.h>
#include <math.h>

#define D        256
#define BM       64
#define ASTRIDEB 528                 // A rows: 16B-aligned (b128 broadcast reads)
#define BSTRIDEB 520                 // B rows: 8B-aligned, 520/4=130 dwords -> 2-way-free b64 reads
#define ATILEB   (BM * ASTRIDEB)     // 33792 B
#define BTILEB   (BM * BSTRIDEB)     // 33280 B

typedef _Float16 h2 __attribute__((ext_vector_type(2)));

__device__ __forceinline__ h2 u2h(unsigned u) { return __builtin_bit_cast(h2, u); }
__device__ __forceinline__ unsigned h2u(h2 h) { return __builtin_bit_cast(unsigned, h); }

__global__ __launch_bounds__(1024, 4)
void jaccard_kernel(const float* __restrict__ A, const float* __restrict__ B,
                    float* __restrict__ out) {
    extern __shared__ char lds[];
    char*  ATile = lds;                                // [64][528 B]
    char*  BTile = lds + ATILEB;                       // [64][520 B]
    float* sums  = (float*)(lds + ATILEB + BTILEB);    // [128]

    const int bi   = blockIdx.x;
    const int bj   = blockIdx.y;
    const int tid  = threadIdx.x;
    const int lane = tid & 63;
    const int wid  = tid >> 6;   // 0..15

    // ---- staging: 128 logical rows over 16 waves; fp32 -> sigmoid -> fp16 ----
    for (int r = wid; r < 2 * BM; r += 16) {
        const bool  isA = (r < BM);
        const int   row = isA ? r : (r - BM);
        const float* src = isA ? (A + (size_t)(bi * BM + row) * D)
                               : (B + (size_t)(bj * BM + row) * D);
        float4 g = *(const float4*)(src + 4 * lane);
        float4 s;
        s.x = 1.0f / (1.0f + __expf(-g.x));
        s.y = 1.0f / (1.0f + __expf(-g.y));
        s.z = 1.0f / (1.0f + __expf(-g.z));
        s.w = 1.0f / (1.0f + __expf(-g.w));

        h2 lo, hi;
        lo.x = (_Float16)s.x; lo.y = (_Float16)s.y;
        hi.x = (_Float16)s.z; hi.y = (_Float16)s.w;

        char* dst = isA ? (ATile + (size_t)row * ASTRIDEB + 8 * lane)
                        : (BTile + (size_t)row * BSTRIDEB + 8 * lane);
        *(uint2*)dst = make_uint2(h2u(lo), h2u(hi));

        // fp32 row sum of the ROUNDED values (keeps union identity consistent)
        float rs = ((float)lo.x + (float)lo.y) + ((float)hi.x + (float)hi.y);
        #pragma unroll
        for (int k = 32; k >= 1; k >>= 1)
            rs += __shfl_xor(rs, k, 64);
        if (lane == 0) sums[r] = rs;
    }
    __syncthreads();

    // ---- main: 2x2 micro-tile; A via b128 broadcast, B via 2-way-free b64 ----
    const int tx = tid & 31;   // cols {tx, tx+32}
    const int ty = tid >> 5;   // rows {ty, ty+32}

    const char* a0 = ATile + (size_t)ty        * ASTRIDEB;
    const char* a1 = ATile + (size_t)(32 + ty) * ASTRIDEB;
    const char* b0 = BTile + (size_t)tx        * BSTRIDEB;
    const char* b1 = BTile + (size_t)(32 + tx) * BSTRIDEB;

    h2 acc00a = {0,0}, acc00b = {0,0};
    h2 acc01a = {0,0}, acc01b = {0,0};
    h2 acc10a = {0,0}, acc10b = {0,0};
    h2 acc11a = {0,0}, acc11b = {0,0};

    // one chunk = 16 B = 8 halfs; 32 chunks cover D=256
    auto chunk = [&](int c, h2& c00, h2& c01, h2& c10, h2& c11) {
        uint4 va0 = *(const uint4*)(a0 + 16 * c);
        uint4 va1 = *(const uint4*)(a1 + 16 * c);
        uint2 vb0l = *(const uint2*)(b0 + 16 * c);
        uint2 vb0h = *(const uint2*)(b0 + 16 * c + 8);
        uint2 vb1l = *(const uint2*)(b1 + 16 * c);
        uint2 vb1h = *(const uint2*)(b1 + 16 * c + 8);
        h2 A0[4] = { u2h(va0.x), u2h(va0.y), u2h(va0.z), u2h(va0.w) };
        h2 A1[4] = { u2h(va1.x), u2h(va1.y), u2h(va1.z), u2h(va1.w) };
        h2 B0[4] = { u2h(vb0l.x), u2h(vb0l.y), u2h(vb0h.x), u2h(vb0h.y) };
        h2 B1[4] = { u2h(vb1l.x), u2h(vb1l.y), u2h(vb1h.x), u2h(vb1h.y) };
        #define COMBO(AV, BV, ACC)                                             \
        {                                                                      \
            h2 m0 = __builtin_elementwise_min(AV[0], BV[0]);                   \
            h2 m1 = __builtin_elementwise_min(AV[1], BV[1]);                   \
            h2 m2 = __builtin_elementwise_min(AV[2], BV[2]);                   \
            h2 m3 = __builtin_elementwise_min(AV[3], BV[3]);                   \
            ACC += (m0 + m1) + (m2 + m3);                                      \
        }
        COMBO(A0, B0, c00) COMBO(A0, B1, c01) COMBO(A1, B0, c10) COMBO(A1, B1, c11)
        #undef COMBO
    };

    #pragma unroll 4
    for (int cc = 0; cc < 16; ++cc) {
        chunk(2 * cc,     acc00a, acc01a, acc10a, acc11a);
        chunk(2 * cc + 1, acc00b, acc01b, acc10b, acc11b);
    }

    // ---- epilogue ----
    const float i00 = ((float)acc00a.x + (float)acc00a.y) + ((float)acc00b.x + (float)acc00b.y);
    const float i01 = ((float)acc01a.x + (float)acc01a.y) + ((float)acc01b.x + (float)acc01b.y);
    const float i10 = ((float)acc10a.x + (float)acc10a.y) + ((float)acc10b.x + (float)acc10b.y);
    const float i11 = ((float)acc11a.x + (float)acc11a.y) + ((float)acc11b.x + (float)acc11b.y);

    const float sa0 = sums[ty],      sa1 = sums[32 + ty];
    const float sb0 = sums[64 + tx], sb1 = sums[96 + tx];

    const float v00 = i00 / (sa0 + sb0 - i00);
    const float v01 = i01 / (sa0 + sb1 - i01);
    const float v10 = i10 / (sa1 + sb0 - i10);
    const float v11 = i11 / (sa1 + sb1 - i11);

    float* outT = out + (size_t)1024 * 1024;
    const int i0 = bi * BM + ty, i1 = i0 + 32;
    const int j0 = bj * BM + tx, j1 = j0 + 32;

    out [(size_t)i0 * 1024 + j0] = v00;
    out [(size_t)i0 * 1024 + j1] = v01;
    out [(size_t)i1 * 1024 + j0] = v10;
    out [(size_t)i1 * 1024 + j1] = v11;
    outT[(size_t)j0 * 1024 + i0] = v00;
    outT[(size_t)j1 * 1024 + i0] = v01;
    outT[(size_t)j0 * 1024 + i1] = v10;
    outT[(size_t)j1 * 1024 + i1] = v11;
}

extern "C" void kernel_launch(void* const* d_in, const int* in_sizes, int n_in,
                              void* d_out, int out_size, void* d_ws, size_t ws_size,
                              hipStream_t stream) {
    const float* x1 = (const float*)d_in[0];
    const float* x2 = (const float*)d_in[1];
    float* out = (float*)d_out;

    const size_t lds_bytes = ATILEB + BTILEB + 128 * sizeof(float);  // ~66 KB
    hipFuncSetAttribute((const void*)jaccard_kernel,
                        hipFuncAttributeMaxDynamicSharedMemorySize, (int)lds_bytes);

    dim3 grid(16, 16);   // 256 blocks = 1 per CU, 16 waves/CU
    jaccard_kernel<<<grid, 1024, lds_bytes, stream>>>(x1, x2, out);
}

// Round 6
// 25.451 us; speedup vs baseline: 1.0384x; 1.0384x over previous
//
#include <hip/hip_runtime.h>
#include <math.h>

#define BM    64
#define ASTR  528                 // A row stride (16B-aligned -> b128 broadcast reads)
#define BSTR  520                 // B row stride (8B-aligned  -> conflict-free b64 reads)
#define AOFF  0
#define BOFF  (BM * ASTR)         // 33792
#define POFF  (BOFF + BM * BSTR)  // 67072: partials, 1024 threads x 72 B
#define PSTR  72
#define SOFF  (POFF + 1024 * PSTR) // 140800: row sums [128] f32
#define LDSZ  (SOFF + 128 * 4)     // 141312 B total

typedef _Float16 h2 __attribute__((ext_vector_type(2)));
__device__ __forceinline__ h2 u2h(unsigned u) { return __builtin_bit_cast(h2, u); }
__device__ __forceinline__ unsigned h2u(h2 h) { return __builtin_bit_cast(unsigned, h); }

__global__ __launch_bounds__(1024, 4)
void jaccard_kernel(const float* __restrict__ A, const float* __restrict__ B,
                    float* __restrict__ out) {
    extern __shared__ char lds[];
    char*  ATile = lds + AOFF;
    char*  BTile = lds + BOFF;
    char*  Part  = lds + POFF;
    float* sums  = (float*)(lds + SOFF);

    const int bi = blockIdx.x, bj = blockIdx.y;
    const int tid = threadIdx.x, lane = tid & 63, wid = tid >> 6;

    // ---- staging: 128 rows over 16 waves; fp32 -> sigmoid -> fp16 + row sums ----
    for (int r = wid; r < 2 * BM; r += 16) {
        const bool  isA = (r < BM);
        const int   row = isA ? r : (r - BM);
        const float* src = isA ? (A + (size_t)(bi * BM + row) * 256)
                               : (B + (size_t)(bj * BM + row) * 256);
        float4 g = *(const float4*)(src + 4 * lane);
        float4 s;
        s.x = 1.0f / (1.0f + __expf(-g.x));
        s.y = 1.0f / (1.0f + __expf(-g.y));
        s.z = 1.0f / (1.0f + __expf(-g.z));
        s.w = 1.0f / (1.0f + __expf(-g.w));
        h2 lo, hi;
        lo.x = (_Float16)s.x; lo.y = (_Float16)s.y;
        hi.x = (_Float16)s.z; hi.y = (_Float16)s.w;
        char* dst = isA ? (ATile + (size_t)row * ASTR + 8 * lane)
                        : (BTile + (size_t)row * BSTR + 8 * lane);
        *(uint2*)dst = make_uint2(h2u(lo), h2u(hi));
        float rs = ((float)lo.x + (float)lo.y) + ((float)hi.x + (float)hi.y);
        #pragma unroll
        for (int k = 32; k >= 1; k >>= 1)
            rs += __shfl_xor(rs, k, 64);
        if (lane == 0) sums[r] = rs;
    }
    __syncthreads();

    // ---- main: 4x4 microtile, D split over 4 quarters, imm-offset reads only ----
    const int s  = tid & 255;     // spatial thread 0..255
    const int q  = tid >> 8;      // D-quarter 0..3: chunks [8q, 8q+8)
    const int tx = s & 15;        // cols {tx + 16n}
    const int ty = s >> 4;        // rows {ty + 16m}

    const char* ab = ATile + ty * ASTR + q * 128;
    const char* bb = BTile + tx * BSTR + q * 128;

    h2 acc[4][4] = {};
    #pragma unroll
    for (int cc = 0; cc < 8; ++cc) {
        uint4 av[4];
        #pragma unroll
        for (int m = 0; m < 4; ++m)
            av[m] = *(const uint4*)(ab + m * (16 * ASTR) + cc * 16);
        uint2 bl[4], bh[4];
        #pragma unroll
        for (int n = 0; n < 4; ++n) {
            bl[n] = *(const uint2*)(bb + n * (16 * BSTR) + cc * 16);
            bh[n] = *(const uint2*)(bb + n * (16 * BSTR) + cc * 16 + 8);
        }
        #pragma unroll
        for (int m = 0; m < 4; ++m) {
            h2 a0 = u2h(av[m].x), a1 = u2h(av[m].y), a2 = u2h(av[m].z), a3 = u2h(av[m].w);
            #pragma unroll
            for (int n = 0; n < 4; ++n) {
                h2 m0 = __builtin_elementwise_min(a0, u2h(bl[n].x));
                h2 m1 = __builtin_elementwise_min(a1, u2h(bl[n].y));
                h2 m2 = __builtin_elementwise_min(a2, u2h(bh[n].x));
                h2 m3 = __builtin_elementwise_min(a3, u2h(bh[n].y));
                acc[m][n] += (m0 + m1) + (m2 + m3);
            }
        }
    }

    // ---- write partials (h2 each), cross-quarter reduce ----
    char* pw = Part + (size_t)(q * 256 + s) * PSTR;
    #pragma unroll
    for (int m = 0; m < 4; ++m) {
        *(uint2*)(pw + m * 16)     = make_uint2(h2u(acc[m][0]), h2u(acc[m][1]));
        *(uint2*)(pw + m * 16 + 8) = make_uint2(h2u(acc[m][2]), h2u(acc[m][3]));
    }
    __syncthreads();

    // epilogue: thread (s,q) owns output row ty+16q, cols {tx+16n}
    float in0 = 0.f, in1 = 0.f, in2 = 0.f, in3 = 0.f;
    #pragma unroll
    for (int qq = 0; qq < 4; ++qq) {
        const char* rp = Part + (size_t)(qq * 256 + s) * PSTR + q * 16;
        uint2 lo = *(const uint2*)rp;
        uint2 hi = *(const uint2*)(rp + 8);
        h2 p0 = u2h(lo.x), p1 = u2h(lo.y), p2 = u2h(hi.x), p3 = u2h(hi.y);
        in0 += (float)p0.x + (float)p0.y;
        in1 += (float)p1.x + (float)p1.y;
        in2 += (float)p2.x + (float)p2.y;
        in3 += (float)p3.x + (float)p3.y;
    }

    const float sa  = sums[ty + 16 * q];
    const float sb0 = sums[64 + tx];
    const float sb1 = sums[64 + tx + 16];
    const float sb2 = sums[64 + tx + 32];
    const float sb3 = sums[64 + tx + 48];

    const float v0 = in0 / (sa + sb0 - in0);
    const float v1 = in1 / (sa + sb1 - in1);
    const float v2 = in2 / (sa + sb2 - in2);
    const float v3 = in3 / (sa + sb3 - in3);

    const int i  = bi * 64 + ty + 16 * q;
    const int j0 = bj * 64 + tx;
    float* outT = out + (size_t)1024 * 1024;

    out[(size_t)i * 1024 + j0]      = v0;
    out[(size_t)i * 1024 + j0 + 16] = v1;
    out[(size_t)i * 1024 + j0 + 32] = v2;
    out[(size_t)i * 1024 + j0 + 48] = v3;
    outT[(size_t)j0        * 1024 + i] = v0;
    outT[(size_t)(j0 + 16) * 1024 + i] = v1;
    outT[(size_t)(j0 + 32) * 1024 + i] = v2;
    outT[(size_t)(j0 + 48) * 1024 + i] = v3;
}

extern "C" void kernel_launch(void* const* d_in, const int* in_sizes, int n_in,
                              void* d_out, int out_size, void* d_ws, size_t ws_size,
                              hipStream_t stream) {
    const float* x1 = (const float*)d_in[0];
    const float* x2 = (const float*)d_in[1];
    float* out = (float*)d_out;

    hipFuncSetAttribute((const void*)jaccard_kernel,
                        hipFuncAttributeMaxDynamicSharedMemorySize, LDSZ);

    dim3 grid(16, 16);   // 256 blocks = 1 per CU, 16 waves/CU
    jaccard_kernel<<<grid, 1024, LDSZ, stream>>>(x1, x2, out);
}